// Round 1
// 440.897 us; speedup vs baseline: 1.0267x; 1.0267x over previous
//
#include <hip/hip_runtime.h>

#define NEGV -10000.0f
#define BB 1024
#define TT 512
#define KK 64

typedef float vf2 __attribute__((ext_vector_type(2)));

// Raw barrier: own-wave LDS drain + s_barrier (NOT __syncthreads: avoids the
// vmcnt(0) drain of the unary prefetch queue).
#define BAR() asm volatile("s_waitcnt lgkmcnt(0)\n\ts_barrier" ::: "memory")

// ---------------------------------------------------------------------------
// K0: trans = log_softmax(A + inv_mask*NEG, axis=-1). (unchanged)
// ---------------------------------------------------------------------------
__global__ __launch_bounds__(64)
void trans_kernel(const float* __restrict__ A, const int* __restrict__ inv,
                  float* __restrict__ trans)
{
    const int i = blockIdx.x, j = threadIdx.x;
    float x = A[i * KK + j] + (inv[i * KK + j] ? NEGV : 0.0f);
    float m = x;
    #pragma unroll
    for (int o = 32; o > 0; o >>= 1) m = fmaxf(m, __shfl_xor(m, o));
    float e = expf(x - m);
    float s = e;
    #pragma unroll
    for (int o = 32; o > 0; o >>= 1) s += __shfl_xor(s, o);
    trans[i * KK + j] = (x - m) - logf(s);
}

// ---------------------------------------------------------------------------
// K1: fused Viterbi. R9 restructure: split the i-axis across LANE HALVES, not
// waves. Lane l of wave w owns output tag j = 32w + (l&31) and covers incoming
// i in [32*(l>>5), 32*(l>>5)+32). The 2x32 merge is an in-wave __shfl_xor(32)
// (2 shuffles + ~5 VALU) instead of {BAR + sMI LDS round-trip + wave0-serial
// merge + BAR}. ONE barrier per step (alpha broadcast) instead of two.
// First-index scan: encode (sv==mw ? i : 32, all inline consts) + v_min3 tree
// — chain ~25cy vs the 124cy serial cndmask chain.
// ---------------------------------------------------------------------------

__device__ __forceinline__ int imin3(int a, int b, int c) { return min(min(a, b), c); }

#define FILL4(BUF_, RB_)                                                       \
  { _Pragma("unroll")                                                          \
    for (int d_ = 0; d_ < 4; ++d_) {                                           \
        int r_ = (RB_) + d_; if (r_ > TT - 1) r_ = TT - 1;                     \
        BUF_[d_] = ur[r_ * KK + j];                                            \
    } }

#define STEP(T_, UV_)                                                          \
  {                                                                            \
    /* sv[il] = alpha_{t-1}[ibase+il] + trans[ibase+il][j] */                  \
    float sv[32];                                                              \
    _Pragma("unroll")                                                          \
    for (int q = 0; q < 8; ++q) {                                              \
        vf2 t01 = vf2{a4[q].x, a4[q].y} + Tr2[2 * q];                          \
        vf2 t23 = vf2{a4[q].z, a4[q].w} + Tr2[2 * q + 1];                      \
        sv[4 * q + 0] = t01.x; sv[4 * q + 1] = t01.y;                          \
        sv[4 * q + 2] = t23.x; sv[4 * q + 3] = t23.y;                          \
    }                                                                          \
    /* half-max tree (v_max3-friendly) */                                      \
    float l0[11];                                                              \
    _Pragma("unroll")                                                          \
    for (int i = 0; i < 10; ++i)                                               \
        l0[i] = fmaxf(fmaxf(sv[3 * i], sv[3 * i + 1]), sv[3 * i + 2]);         \
    l0[10] = fmaxf(sv[30], sv[31]);                                            \
    float l1a = fmaxf(fmaxf(l0[0], l0[1]), l0[2]);                             \
    float l1b = fmaxf(fmaxf(l0[3], l0[4]), l0[5]);                             \
    float l1c = fmaxf(fmaxf(l0[6], l0[7]), l0[8]);                             \
    float l1d = fmaxf(l0[9], l0[10]);                                          \
    float mw  = fmaxf(fmaxf(fmaxf(l1a, l1b), l1c), l1d);                       \
    /* first-index: independent encode (inline consts only) + v_min3 tree */   \
    int c[32];                                                                 \
    _Pragma("unroll")                                                          \
    for (int i = 0; i < 32; ++i) c[i] = (sv[i] == mw) ? i : 32;                \
    int n0[11];                                                                \
    _Pragma("unroll")                                                          \
    for (int i = 0; i < 10; ++i)                                               \
        n0[i] = imin3(c[3 * i], c[3 * i + 1], c[3 * i + 2]);                   \
    n0[10] = min(c[30], c[31]);                                                \
    int n1a = imin3(n0[0], n0[1], n0[2]);                                      \
    int n1b = imin3(n0[3], n0[4], n0[5]);                                      \
    int n1c = imin3(n0[6], n0[7], n0[8]);                                      \
    int n1d = min(n0[9], n0[10]);                                              \
    int gidx = min(min(min(n1a, n1b), n1c), n1d) + ibase;                      \
    /* in-wave cross-half merge; ties -> lo half = smaller global i (exact) */ \
    float mo = __shfl_xor(mw, 32);                                             \
    int   go = __shfl_xor(gidx, 32);                                           \
    bool take = ishi ? (mo >= mw) : (mo > mw);                                 \
    float m  = fmaxf(mw, mo);                                                  \
    int  bpi = take ? go : gidx;                                               \
    float u_ = (UV_);                                                          \
    asm volatile("" : "+v"(u_));                                               \
    if ((T_) <= len) alpha = m + u_;     /* len uniform -> scalar branch */    \
    if (!ishi) sA[j] = alpha;            /* lo lanes: alpha broadcast  */      \
    else if ((T_) >= 2 && (T_) <= len)                                         \
        sbp[((T_) - 2) * KK + j] = (unsigned char)bpi; /* hi lanes: bp */      \
    BAR(); /* single barrier: both waves' sA halves + bp visible */            \
    {                                                                          \
        const float4* p = (const float4*)sA + (ibase >> 2);                    \
        _Pragma("unroll")                                                      \
        for (int q = 0; q < 8; ++q) a4[q] = p[q];                              \
    }                                                                          \
  }

__global__ __launch_bounds__(128, 2)
void viterbi_kernel(const float* __restrict__ unary, const int* __restrict__ lengths,
                    const float* __restrict__ trans, int* __restrict__ out)
{
    const int tid   = threadIdx.x;
    const int wv    = tid >> 6;                    // wave id 0/1
    const int lane  = tid & 63;
    const int sub   = lane & 31;
    const int ibase = (lane >> 5) << 5;            // incoming-tag base: 0 or 32
    const bool ishi = (lane >= 32);
    const int j     = wv * 32 + sub;               // output tag owned by lane
    const int b     = blockIdx.x;

    __shared__ unsigned char sbp[(TT - 1) * KK];   // bp rows t=2..512
    __shared__ __align__(16) float sA[KK];         // alpha broadcast

    // Tr2[q] = {trans[ibase+2q][j], trans[ibase+2q+1][j]}
    vf2 Tr2[16];
    #pragma unroll
    for (int q = 0; q < 16; ++q) {
        Tr2[q].x = trans[(ibase + 2 * q)     * KK + j];
        Tr2[q].y = trans[(ibase + 2 * q + 1) * KK + j];
    }

    const int len = lengths[b];                    // 1..512, uniform per block
    const float* ur = unary + (long)b * (TT * KK);
    int* orow = out + b * TT;

    // unary prefetch (both waves; each loads its own j-half), double-buffered
    float ub0[4], ub1[4];
    FILL4(ub0, 0) FILL4(ub1, 4)                    // rows 0..7 for t=1..8

    float alpha = (j == 1) ? 0.0f : NEGV;          // GO frame
    if (!ishi) sA[j] = alpha;                      // wv0 -> sA[0:32), wv1 -> sA[32:64)
    BAR();

    float4 a4[8];                                  // this lane-half's broadcast
    {
        const float4* p = (const float4*)sA + (ibase >> 2);
        #pragma unroll
        for (int q = 0; q < 8; ++q) a4[q] = p[q];
    }

    for (int tb = 1; tb <= len; tb += 8) {
        STEP(tb + 0, ub0[0]) STEP(tb + 1, ub0[1])
        STEP(tb + 2, ub0[2]) STEP(tb + 3, ub0[3])
        FILL4(ub0, tb + 7)                         // rows for t = tb+8..tb+11
        STEP(tb + 4, ub1[0]) STEP(tb + 5, ub1[1])
        STEP(tb + 6, ub1[2]) STEP(tb + 7, ub1[3])
        FILL4(ub1, tb + 11)                        // rows for t = tb+12..tb+15
    }

    if (wv == 1) return;                           // no barriers after the loop

    // last = first-index argmax of final alpha (read full vector from sA;
    // final STEP's BAR made both halves visible)
    float av = sA[lane];
    float mm = av;
    #pragma unroll
    for (int o = 32; o > 0; o >>= 1) mm = fmaxf(mm, __shfl_xor(mm, o));
    unsigned long long msk = __ballot(av == mm);
    int last = __ffsll(msk) - 1;

    for (int jj = len - 1 + lane; jj < TT; jj += 64) orow[jj] = last;

    asm volatile("s_waitcnt lgkmcnt(0)" ::: "memory");   // settle own DS queue

    // backward: pure LDS pointer chase (wave0)
    int tag = last;
    for (int t = len; t >= 2; --t) {
        int prev = sbp[(t - 2) * KK + tag];        // same-address broadcast read
        if (lane == 0) orow[t - 2] = prev;
        tag = prev;
    }
}

extern "C" void kernel_launch(void* const* d_in, const int* in_sizes, int n_in,
                              void* d_out, int out_size, void* d_ws, size_t ws_size,
                              hipStream_t stream)
{
    const float* unary   = (const float*)d_in[0];
    const int*   lengths = (const int*)d_in[1];
    const int*   inv     = (const int*)d_in[2];
    const float* A       = (const float*)d_in[3];
    int*         out     = (int*)d_out;

    float* trans = (float*)d_ws;                   // 4096 floats = 16 KB

    trans_kernel<<<KK, KK, 0, stream>>>(A, inv, trans);
    viterbi_kernel<<<BB, 128, 0, stream>>>(unary, lengths, trans, out);
}

// Round 4
// 434.575 us; speedup vs baseline: 1.0416x; 1.0145x over previous
//
#include <hip/hip_runtime.h>

#define NEGV -10000.0f
#define BB 1024
#define TT 512
#define KK 64

typedef float vf2 __attribute__((ext_vector_type(2)));
typedef int   vi2 __attribute__((ext_vector_type(2)));

// Raw barrier: own-wave LDS drain + s_barrier (NOT __syncthreads: avoids the
// vmcnt(0) drain of the unary prefetch queue).
#define BAR() asm volatile("s_waitcnt lgkmcnt(0)\n\ts_barrier" ::: "memory")

// ---------------------------------------------------------------------------
// Cross-half pair merges via __builtin_amdgcn_permlane32_swap.
// R10/R11 POST-MORTEM: hand-written asm {v_mov; v_permlane32_swap; v_max}
// failed identically twice (absmax 96 = sentinel 64+ibase leaking into sbp
// => swap produced stale data). gfx950 has VALU->permlane_swap RAW hazards
// needing wait states; inside one asm block hazard NOPs are OUR job and were
// missing. The builtin path lets the compiler model the instruction (returns
// BOTH post-swap registers) and insert hazard handling (T12 recipe).
// With equal inputs v,v the two results per lane form the unordered pair
// {v[l&31], v[32|(l&31)]} under either swap orientation, so fmax/min of them
// is the exact cross-half merge, identical across the (l, l^32) pair.
// ---------------------------------------------------------------------------
__device__ __forceinline__ float merge_max64(float v)
{
    vi2 r = __builtin_amdgcn_permlane32_swap(__float_as_int(v), __float_as_int(v),
                                             false, false);
    return fmaxf(__int_as_float(r[0]), __int_as_float(r[1]));
}
__device__ __forceinline__ int merge_min64(int v)
{
    vi2 r = __builtin_amdgcn_permlane32_swap(v, v, false, false);
    return min(r[0], r[1]);
}

// ---------------------------------------------------------------------------
// K0: trans = log_softmax(A + inv_mask*NEG, axis=-1). (unchanged)
// ---------------------------------------------------------------------------
__global__ __launch_bounds__(64)
void trans_kernel(const float* __restrict__ A, const int* __restrict__ inv,
                  float* __restrict__ trans)
{
    const int i = blockIdx.x, j = threadIdx.x;
    float x = A[i * KK + j] + (inv[i * KK + j] ? NEGV : 0.0f);
    float m = x;
    #pragma unroll
    for (int o = 32; o > 0; o >>= 1) m = fmaxf(m, __shfl_xor(m, o));
    float e = expf(x - m);
    float s = e;
    #pragma unroll
    for (int o = 32; o > 0; o >>= 1) s += __shfl_xor(s, o);
    trans[i * KK + j] = (x - m) - logf(s);
}

// ---------------------------------------------------------------------------
// K1: fused Viterbi. Lane l of wave w: output tag j = 32w + (l&31), incoming
// i in [32*(l>>5), 32*(l>>5)+32). Cross-half merges via permlane32_swap
// builtin (VALU, ~6cy) instead of ds_bpermute (~120cy LDS latency); sA
// double-buffered by step parity (one barrier per step, no same-interval
// write/read race); index encoded against the MERGED max m with sentinel 64
// (inline const), local min tree, +ibase, permlane min merge — exact global
// first-index tie-break (min over encoded global indices = first argmax).
// ---------------------------------------------------------------------------

__device__ __forceinline__ int imin3(int a, int b, int c) { return min(min(a, b), c); }

#define FILL4(BUF_, RB_)                                                       \
  { _Pragma("unroll")                                                          \
    for (int d_ = 0; d_ < 4; ++d_) {                                           \
        int r_ = (RB_) + d_; if (r_ > TT - 1) r_ = TT - 1;                     \
        BUF_[d_] = ur[r_ * KK + j];                                            \
    } }

// P_ = (T_) & 1, compile-time. Step t writes+reads sA[P_]; the previous step
// used sA[P_^1], so reads(t-1) and writes(t) in one barrier interval touch
// different buffers.
#define STEP(T_, UV_, P_)                                                      \
  {                                                                            \
    /* sv[il] = alpha_{t-1}[ibase+il] + trans[ibase+il][j] */                  \
    float sv[32];                                                              \
    _Pragma("unroll")                                                          \
    for (int q = 0; q < 8; ++q) {                                              \
        vf2 t01 = vf2{a4[q].x, a4[q].y} + Tr2[2 * q];                          \
        vf2 t23 = vf2{a4[q].z, a4[q].w} + Tr2[2 * q + 1];                      \
        sv[4 * q + 0] = t01.x; sv[4 * q + 1] = t01.y;                          \
        sv[4 * q + 2] = t23.x; sv[4 * q + 3] = t23.y;                          \
    }                                                                          \
    /* half-max tree (v_max3-friendly) */                                      \
    float l0[11];                                                              \
    _Pragma("unroll")                                                          \
    for (int i = 0; i < 10; ++i)                                               \
        l0[i] = fmaxf(fmaxf(sv[3 * i], sv[3 * i + 1]), sv[3 * i + 2]);         \
    l0[10] = fmaxf(sv[30], sv[31]);                                            \
    float l1a = fmaxf(fmaxf(l0[0], l0[1]), l0[2]);                             \
    float l1b = fmaxf(fmaxf(l0[3], l0[4]), l0[5]);                             \
    float l1c = fmaxf(fmaxf(l0[6], l0[7]), l0[8]);                             \
    float l1d = fmaxf(l0[9], l0[10]);                                          \
    float mw  = fmaxf(fmaxf(fmaxf(l1a, l1b), l1c), l1d);                       \
    /* cross-half max merge: VALU permlane pair merge */                       \
    const float m = merge_max64(mw);            /* merged max over all 64 i */ \
    /* first-index vs merged m: sentinel 64 (inline const), then +ibase */     \
    int c[32];                                                                 \
    _Pragma("unroll")                                                          \
    for (int i = 0; i < 32; ++i) c[i] = (sv[i] == m) ? i : 64;                 \
    int n0[11];                                                                \
    _Pragma("unroll")                                                          \
    for (int i = 0; i < 10; ++i)                                               \
        n0[i] = imin3(c[3 * i], c[3 * i + 1], c[3 * i + 2]);                   \
    n0[10] = min(c[30], c[31]);                                                \
    int n1a = imin3(n0[0], n0[1], n0[2]);                                      \
    int n1b = imin3(n0[3], n0[4], n0[5]);                                      \
    int n1c = imin3(n0[6], n0[7], n0[8]);                                      \
    int n1d = min(n0[9], n0[10]);                                              \
    int cmin = min(min(min(n1a, n1b), n1c), n1d) + ibase;                      \
    int bpi = merge_min64(cmin);                /* global first argmax */      \
    float u_ = (UV_);                                                          \
    asm volatile("" : "+v"(u_));                                               \
    if ((T_) <= len) alpha = m + u_;     /* len uniform -> scalar branch */    \
    if (!ishi) sA[P_][j] = alpha;        /* lo lanes: alpha broadcast  */      \
    else if ((T_) >= 2 && (T_) <= len)                                         \
        sbp[((T_) - 2) * KK + j] = (unsigned char)bpi; /* hi lanes: bp */      \
    BAR(); /* both waves' sA[P_] halves + bp visible */                        \
    {                                                                          \
        const float4* p = (const float4*)sA[P_] + (ibase >> 2);                \
        _Pragma("unroll")                                                      \
        for (int q = 0; q < 8; ++q) a4[q] = p[q];                              \
    }                                                                          \
  }

__global__ __launch_bounds__(128, 2)
void viterbi_kernel(const float* __restrict__ unary, const int* __restrict__ lengths,
                    const float* __restrict__ trans, int* __restrict__ out)
{
    const int tid   = threadIdx.x;
    const int wv    = tid >> 6;                    // wave id 0/1
    const int lane  = tid & 63;
    const int sub   = lane & 31;
    const int ibase = (lane >> 5) << 5;            // incoming-tag base: 0 or 32
    const bool ishi = (lane >= 32);
    const int j     = wv * 32 + sub;               // output tag owned by lane
    const int b     = blockIdx.x;

    __shared__ unsigned char sbp[(TT - 1) * KK];   // bp rows t=2..512
    __shared__ __align__(16) float sA[2][KK];      // alpha broadcast, dbuf by parity

    // Tr2[q] = {trans[ibase+2q][j], trans[ibase+2q+1][j]}
    vf2 Tr2[16];
    #pragma unroll
    for (int q = 0; q < 16; ++q) {
        Tr2[q].x = trans[(ibase + 2 * q)     * KK + j];
        Tr2[q].y = trans[(ibase + 2 * q + 1) * KK + j];
    }

    const int len = lengths[b];                    // 1..512, uniform per block
    const float* ur = unary + (long)b * (TT * KK);
    int* orow = out + b * TT;

    // unary prefetch (both waves; each loads its own j-half), double-buffered
    float ub0[4], ub1[4];
    FILL4(ub0, 0) FILL4(ub1, 4)                    // rows 0..7 for t=1..8

    float alpha = (j == 1) ? 0.0f : NEGV;          // GO frame
    if (!ishi) sA[0][j] = alpha;                   // initial state -> buffer 0
    BAR();

    float4 a4[8];                                  // this lane-half's broadcast
    {
        const float4* p = (const float4*)sA[0] + (ibase >> 2);
        #pragma unroll
        for (int q = 0; q < 8; ++q) a4[q] = p[q];
    }

    // tb = 1, 9, 17, ... -> t = tb+d has parity (d+1)&1
    for (int tb = 1; tb <= len; tb += 8) {
        STEP(tb + 0, ub0[0], 1) STEP(tb + 1, ub0[1], 0)
        STEP(tb + 2, ub0[2], 1) STEP(tb + 3, ub0[3], 0)
        FILL4(ub0, tb + 7)                         // rows for t = tb+8..tb+11
        STEP(tb + 4, ub1[0], 1) STEP(tb + 5, ub1[1], 0)
        STEP(tb + 6, ub1[2], 1) STEP(tb + 7, ub1[3], 0)
        FILL4(ub1, tb + 11)                        // rows for t = tb+12..tb+15
    }
    // last executed step t = 8*ceil(len/8): even -> final alphas are in sA[0]

    if (wv == 1) return;                           // no barriers after the loop

    // last = first-index argmax of final alpha (full vector from sA[0])
    float av = sA[0][lane];
    float mm = av;
    #pragma unroll
    for (int o = 32; o > 0; o >>= 1) mm = fmaxf(mm, __shfl_xor(mm, o));
    unsigned long long msk = __ballot(av == mm);
    int last = __ffsll(msk) - 1;

    for (int jj = len - 1 + lane; jj < TT; jj += 64) orow[jj] = last;

    asm volatile("s_waitcnt lgkmcnt(0)" ::: "memory");   // settle own DS queue

    // backward: pure LDS pointer chase (wave0)
    int tag = last;
    for (int t = len; t >= 2; --t) {
        int prev = sbp[(t - 2) * KK + tag];        // same-address broadcast read
        if (lane == 0) orow[t - 2] = prev;
        tag = prev;
    }
}

extern "C" void kernel_launch(void* const* d_in, const int* in_sizes, int n_in,
                              void* d_out, int out_size, void* d_ws, size_t ws_size,
                              hipStream_t stream)
{
    const float* unary   = (const float*)d_in[0];
    const int*   lengths = (const int*)d_in[1];
    const int*   inv     = (const int*)d_in[2];
    const float* A       = (const float*)d_in[3];
    int*         out     = (int*)d_out;

    float* trans = (float*)d_ws;                   // 4096 floats = 16 KB

    trans_kernel<<<KK, KK, 0, stream>>>(A, inv, trans);
    viterbi_kernel<<<BB, 128, 0, stream>>>(unary, lengths, trans, out);
}

// Round 5
// 426.303 us; speedup vs baseline: 1.0618x; 1.0194x over previous
//
#include <hip/hip_runtime.h>

#define NEGV -10000.0f
#define BB 1024
#define TT 512
#define KK 64

typedef float vf2 __attribute__((ext_vector_type(2)));
typedef int   vi2 __attribute__((ext_vector_type(2)));

// Raw barrier: own-wave LDS drain + s_barrier (NOT __syncthreads: avoids the
// vmcnt(0) drain of the unary prefetch queue).
#define BAR() asm volatile("s_waitcnt lgkmcnt(0)\n\ts_barrier" ::: "memory")

// ---------------------------------------------------------------------------
// Cross-half pair merges via __builtin_amdgcn_permlane32_swap (R12-verified).
// With equal inputs v,v the two results per lane form the unordered pair
// {v[l&31], v[32|(l&31)]} under either swap orientation, so fmax/min of them
// is the exact cross-half merge, identical across the (l, l^32) pair.
// (Hand-written asm versions failed: VALU->permlane RAW hazard NOPs are the
// programmer's job inside an asm block; builtin lets the compiler handle it.)
// ---------------------------------------------------------------------------
__device__ __forceinline__ float merge_max64(float v)
{
    vi2 r = __builtin_amdgcn_permlane32_swap(__float_as_int(v), __float_as_int(v),
                                             false, false);
    return fmaxf(__int_as_float(r[0]), __int_as_float(r[1]));
}
__device__ __forceinline__ int merge_min64(int v)
{
    vi2 r = __builtin_amdgcn_permlane32_swap(v, v, false, false);
    return min(r[0], r[1]);
}

// ---------------------------------------------------------------------------
// K0: trans = log_softmax(A + inv_mask*NEG, axis=-1). (unchanged)
// ---------------------------------------------------------------------------
__global__ __launch_bounds__(64)
void trans_kernel(const float* __restrict__ A, const int* __restrict__ inv,
                  float* __restrict__ trans)
{
    const int i = blockIdx.x, j = threadIdx.x;
    float x = A[i * KK + j] + (inv[i * KK + j] ? NEGV : 0.0f);
    float m = x;
    #pragma unroll
    for (int o = 32; o > 0; o >>= 1) m = fmaxf(m, __shfl_xor(m, o));
    float e = expf(x - m);
    float s = e;
    #pragma unroll
    for (int o = 32; o > 0; o >>= 1) s += __shfl_xor(s, o);
    trans[i * KK + j] = (x - m) - logf(s);
}

// ---------------------------------------------------------------------------
// K1: fused Viterbi. Lane l of wave w: output tag j = 32w + (l&31), incoming
// i in [32*(l>>5), 32*(l>>5)+32).
// R13: DEFER the index/backpointer pipeline past the barrier. R12 calibration:
// per-step wall 1348cy, VALU issue 480cy (VALUBusy 34.5% matches) -> ~870cy
// serial latency. sbp[t] is only read AFTER the loop (backward chase), so the
// ~56-instr encode/min-tree/merge/bp-write moves to the post-barrier shadow,
// overlapping the next step's a4 ds_read latency and the partner wave's
// pre-barrier phase. Pre-barrier path: adds -> max tree -> permlane merge ->
// alpha -> sA write -> BAR (~55 instr). sv[]/m stay live across the barrier
// (+~32 VGPR, fine at 2 waves/SIMD). Deferred sbp writes drain at the NEXT
// BAR; one post-loop BAR publishes the final rows to wave0's backward pass.
// ---------------------------------------------------------------------------

__device__ __forceinline__ int imin3(int a, int b, int c) { return min(min(a, b), c); }

#define FILL4(BUF_, RB_)                                                       \
  { _Pragma("unroll")                                                          \
    for (int d_ = 0; d_ < 4; ++d_) {                                           \
        int r_ = (RB_) + d_; if (r_ > TT - 1) r_ = TT - 1;                     \
        BUF_[d_] = ur[r_ * KK + j];                                            \
    } }

// P_ = (T_) & 1, compile-time. Step t writes+reads sA[P_]; the previous step
// used sA[P_^1], so reads(t-1) and writes(t) in one barrier interval touch
// different buffers. bp writes for step t land in interval t+1 (deferred).
#define STEP(T_, UV_, P_)                                                      \
  {                                                                            \
    /* ---- Phase A (pre-barrier critical path) ---- */                        \
    /* sv[il] = alpha_{t-1}[ibase+il] + trans[ibase+il][j] */                  \
    float sv[32];                                                              \
    _Pragma("unroll")                                                          \
    for (int q = 0; q < 8; ++q) {                                              \
        vf2 t01 = vf2{a4[q].x, a4[q].y} + Tr2[2 * q];                          \
        vf2 t23 = vf2{a4[q].z, a4[q].w} + Tr2[2 * q + 1];                      \
        sv[4 * q + 0] = t01.x; sv[4 * q + 1] = t01.y;                          \
        sv[4 * q + 2] = t23.x; sv[4 * q + 3] = t23.y;                          \
    }                                                                          \
    /* half-max tree (v_max3-friendly) */                                      \
    float l0[11];                                                              \
    _Pragma("unroll")                                                          \
    for (int i = 0; i < 10; ++i)                                               \
        l0[i] = fmaxf(fmaxf(sv[3 * i], sv[3 * i + 1]), sv[3 * i + 2]);         \
    l0[10] = fmaxf(sv[30], sv[31]);                                            \
    float l1a = fmaxf(fmaxf(l0[0], l0[1]), l0[2]);                             \
    float l1b = fmaxf(fmaxf(l0[3], l0[4]), l0[5]);                             \
    float l1c = fmaxf(fmaxf(l0[6], l0[7]), l0[8]);                             \
    float l1d = fmaxf(l0[9], l0[10]);                                          \
    float mw  = fmaxf(fmaxf(fmaxf(l1a, l1b), l1c), l1d);                       \
    const float m = merge_max64(mw);            /* merged max over all 64 i */ \
    float u_ = (UV_);                                                          \
    asm volatile("" : "+v"(u_));                                               \
    if ((T_) <= len) alpha = m + u_;     /* len uniform -> scalar branch */    \
    if (!ishi) sA[P_][j] = alpha;        /* lo lanes: alpha broadcast  */      \
    BAR(); /* both waves' sA[P_] halves visible */                             \
    /* ---- Phase B (post-barrier shadow) ---- */                              \
    /* next a4 first: longest-latency op leads the interval */                 \
    {                                                                          \
        const float4* p = (const float4*)sA[P_] + (ibase >> 2);                \
        _Pragma("unroll")                                                      \
        for (int q = 0; q < 8; ++q) a4[q] = p[q];                              \
    }                                                                          \
    /* deferred index: first-index vs merged m, sentinel 64, +ibase, merge */  \
    {                                                                          \
        int c[32];                                                             \
        _Pragma("unroll")                                                      \
        for (int i = 0; i < 32; ++i) c[i] = (sv[i] == m) ? i : 64;             \
        int n0[11];                                                            \
        _Pragma("unroll")                                                      \
        for (int i = 0; i < 10; ++i)                                           \
            n0[i] = imin3(c[3 * i], c[3 * i + 1], c[3 * i + 2]);               \
        n0[10] = min(c[30], c[31]);                                            \
        int n1a = imin3(n0[0], n0[1], n0[2]);                                  \
        int n1b = imin3(n0[3], n0[4], n0[5]);                                  \
        int n1c = imin3(n0[6], n0[7], n0[8]);                                  \
        int n1d = min(n0[9], n0[10]);                                          \
        int cmin = min(min(min(n1a, n1b), n1c), n1d) + ibase;                  \
        int bpi = merge_min64(cmin);            /* global first argmax */      \
        if (ishi && (T_) >= 2 && (T_) <= len)                                  \
            sbp[((T_) - 2) * KK + j] = (unsigned char)bpi; /* hi lanes: bp */  \
    }                                                                          \
  }

__global__ __launch_bounds__(128, 2)
void viterbi_kernel(const float* __restrict__ unary, const int* __restrict__ lengths,
                    const float* __restrict__ trans, int* __restrict__ out)
{
    const int tid   = threadIdx.x;
    const int wv    = tid >> 6;                    // wave id 0/1
    const int lane  = tid & 63;
    const int sub   = lane & 31;
    const int ibase = (lane >> 5) << 5;            // incoming-tag base: 0 or 32
    const bool ishi = (lane >= 32);
    const int j     = wv * 32 + sub;               // output tag owned by lane
    const int b     = blockIdx.x;

    __shared__ unsigned char sbp[(TT - 1) * KK];   // bp rows t=2..512
    __shared__ __align__(16) float sA[2][KK];      // alpha broadcast, dbuf by parity

    // Tr2[q] = {trans[ibase+2q][j], trans[ibase+2q+1][j]}
    vf2 Tr2[16];
    #pragma unroll
    for (int q = 0; q < 16; ++q) {
        Tr2[q].x = trans[(ibase + 2 * q)     * KK + j];
        Tr2[q].y = trans[(ibase + 2 * q + 1) * KK + j];
    }

    const int len = lengths[b];                    // 1..512, uniform per block
    const float* ur = unary + (long)b * (TT * KK);
    int* orow = out + b * TT;

    // unary prefetch (both waves; each loads its own j-half), double-buffered
    float ub0[4], ub1[4];
    FILL4(ub0, 0) FILL4(ub1, 4)                    // rows 0..7 for t=1..8

    float alpha = (j == 1) ? 0.0f : NEGV;          // GO frame
    if (!ishi) sA[0][j] = alpha;                   // initial state -> buffer 0
    BAR();

    float4 a4[8];                                  // this lane-half's broadcast
    {
        const float4* p = (const float4*)sA[0] + (ibase >> 2);
        #pragma unroll
        for (int q = 0; q < 8; ++q) a4[q] = p[q];
    }

    // tb = 1, 9, 17, ... -> t = tb+d has parity (d+1)&1
    for (int tb = 1; tb <= len; tb += 8) {
        STEP(tb + 0, ub0[0], 1) STEP(tb + 1, ub0[1], 0)
        STEP(tb + 2, ub0[2], 1) STEP(tb + 3, ub0[3], 0)
        FILL4(ub0, tb + 7)                         // rows for t = tb+8..tb+11
        STEP(tb + 4, ub1[0], 1) STEP(tb + 5, ub1[1], 0)
        STEP(tb + 6, ub1[2], 1) STEP(tb + 7, ub1[3], 0)
        FILL4(ub1, tb + 11)                        // rows for t = tb+12..tb+15
    }
    // last executed step t = 8*ceil(len/8): even -> final alphas are in sA[0]

    BAR();  // publish deferred sbp writes of the final steps across waves

    if (wv == 1) return;                           // wave1 done

    // last = first-index argmax of final alpha (full vector from sA[0])
    float av = sA[0][lane];
    float mm = av;
    #pragma unroll
    for (int o = 32; o > 0; o >>= 1) mm = fmaxf(mm, __shfl_xor(mm, o));
    unsigned long long msk = __ballot(av == mm);
    int last = __ffsll(msk) - 1;

    for (int jj = len - 1 + lane; jj < TT; jj += 64) orow[jj] = last;

    asm volatile("s_waitcnt lgkmcnt(0)" ::: "memory");   // settle own DS queue

    // backward: pure LDS pointer chase (wave0)
    int tag = last;
    for (int t = len; t >= 2; --t) {
        int prev = sbp[(t - 2) * KK + tag];        // same-address broadcast read
        if (lane == 0) orow[t - 2] = prev;
        tag = prev;
    }
}

extern "C" void kernel_launch(void* const* d_in, const int* in_sizes, int n_in,
                              void* d_out, int out_size, void* d_ws, size_t ws_size,
                              hipStream_t stream)
{
    const float* unary   = (const float*)d_in[0];
    const int*   lengths = (const int*)d_in[1];
    const int*   inv     = (const int*)d_in[2];
    const float* A       = (const float*)d_in[3];
    int*         out     = (int*)d_out;

    float* trans = (float*)d_ws;                   // 4096 floats = 16 KB

    trans_kernel<<<KK, KK, 0, stream>>>(A, inv, trans);
    viterbi_kernel<<<BB, 128, 0, stream>>>(unary, lengths, trans, out);
}